// Round 3
// baseline (425.889 us; speedup 1.0000x reference)
//
#include <hip/hip_runtime.h>
#include <cfloat>
#include <cmath>

#define NB 8
#define NPTS 4096
#define NCH 256
#define NDIM 1024

// ---------- block reduce helpers (blockDim.x == 256) ----------
__device__ __forceinline__ float blockSum(float v, float* red) {
  for (int off = 32; off; off >>= 1) v += __shfl_down(v, off);
  __syncthreads();
  if ((threadIdx.x & 63) == 0) red[threadIdx.x >> 6] = v;
  __syncthreads();
  return red[0] + red[1] + red[2] + red[3];
}
__device__ __forceinline__ float blockMin(float v, float* red) {
  for (int off = 32; off; off >>= 1) v = fminf(v, __shfl_down(v, off));
  __syncthreads();
  if ((threadIdx.x & 63) == 0) red[threadIdx.x >> 6] = v;
  __syncthreads();
  return fminf(fminf(red[0], red[1]), fminf(red[2], red[3]));
}
__device__ __forceinline__ float blockMax(float v, float* red) {
  for (int off = 32; off; off >>= 1) v = fmaxf(v, __shfl_down(v, off));
  __syncthreads();
  if ((threadIdx.x & 63) == 0) red[threadIdx.x >> 6] = v;
  __syncthreads();
  return fmaxf(fmaxf(red[0], red[1]), fmaxf(red[2], red[3]));
}

// ---------- SoA transpose of the two point clouds ----------
// soa layout (floats): xo[32768] yo[32768] zo[32768] xg[32768] yg[32768] zg[32768]
__global__ __launch_bounds__(256) void prep_soa_kernel(const float* __restrict__ orig,
                                                       const float* __restrict__ gen,
                                                       float* __restrict__ soa) {
  int p = blockIdx.x * 256 + threadIdx.x;   // 0..65535
  int q = p & 32767;
  const float* src = (p < 32768) ? orig : gen;
  float a = src[3 * q], b = src[3 * q + 1], c = src[3 * q + 2];
  float* dst = soa + ((p < 32768) ? 0 : 98304);
  dst[q] = a;
  dst[q + 32768] = b;
  dst[q + 65536] = c;
}

// ---------- diffusion MSE ----------
__global__ __launch_bounds__(256) void diff_kernel(const float4* __restrict__ a,
                                                   const float4* __restrict__ b,
                                                   double* __restrict__ acc) {
  __shared__ float red[4];
  int t = blockIdx.x * 256 + threadIdx.x;
  float4 x = a[t], y = b[t];
  float dx = x.x - y.x, dy = x.y - y.y, dz = x.z - y.z, dw = x.w - y.w;
  float s = dx * dx + dy * dy + dz * dz + dw * dw;
  s = blockSum(s, red);
  if (threadIdx.x == 0) atomicAdd(acc + 0, (double)s);
}

// ---------- style ----------
__global__ __launch_bounds__(256) void style_kernel(const float* __restrict__ a,
                                                    const float* __restrict__ b,
                                                    double* __restrict__ acc) {
  __shared__ float red[4];
  int bb = blockIdx.x;
  const float* pa = a + bb * NDIM;
  const float* pb = b + bb * NDIM;
  float dot = 0.f, na = 0.f, nb = 0.f;
  for (int j = threadIdx.x; j < NDIM; j += 256) {
    float x = pa[j], y = pb[j];
    dot += x * y; na += x * x; nb += y * y;
  }
  dot = blockSum(dot, red);
  na = blockSum(na, red);
  nb = blockSum(nb, red);
  if (threadIdx.x == 0) {
    float nA = fmaxf(sqrtf(na), 1e-8f);
    float nB = fmaxf(sqrtf(nb), 1e-8f);
    float cosv = dot / (nA * nB);
    atomicAdd(acc + 5, (double)fabsf(cosv - 0.5f));
  }
}

// ---------- content: one block per (b,c) row of 4096; partials to scratch ----------
__global__ __launch_bounds__(256) void content_kernel(const float4* __restrict__ o,
                                                      const float4* __restrict__ n,
                                                      float* __restrict__ cpart) {
  __shared__ float red[4];
  size_t row = blockIdx.x;
  const float4* op = o + row * (NPTS / 4);
  const float4* np_ = n + row * (NPTS / 4);
  float so = 0.f, so2 = 0.f, sabs = 0.f, sn = 0.f, sn2 = 0.f, sqd = 0.f;
  for (int c = 0; c < 4; c++) {
    float4 vo = op[c * 256 + threadIdx.x];
    float4 vn = np_[c * 256 + threadIdx.x];
#define DO_COMP(f) { float x = vo.f, y = vn.f; so += x; so2 += x * x; sabs += fabsf(x); \
                     sn += y; sn2 += y * y; float d = y - x; sqd += d * d; }
    DO_COMP(x) DO_COMP(y) DO_COMP(z) DO_COMP(w)
#undef DO_COMP
  }
  so = blockSum(so, red);  so2 = blockSum(so2, red);  sabs = blockSum(sabs, red);
  sn = blockSum(sn, red);  sn2 = blockSum(sn2, red);  sqd = blockSum(sqd, red);
  if (threadIdx.x == 0) {
    float inv = 1.0f / (NPTS - 1);
    float varo = (so2 - so * so * (1.0f / NPTS)) * inv;
    float varn = (sn2 - sn * sn * (1.0f / NPTS)) * inv;
    cpart[row] = sqd;
    cpart[2048 + row] = varo;
    cpart[4096 + row] = varn;
    cpart[6144 + row] = sabs;
  }
}

// ---------- shape: one block per batch, SoA coalesced reads ----------
__global__ __launch_bounds__(256) void shape_kernel(const float* __restrict__ soa,
                                                    float* __restrict__ sv) {
  __shared__ float red[4];
  int bb = blockIdx.x;
  const float* xo = soa + bb * NPTS;
  const float* yo = soa + 32768 + bb * NPTS;
  const float* zo = soa + 65536 + bb * NPTS;
  const float* xg = soa + 98304 + bb * NPTS;
  const float* yg = soa + 131072 + bb * NPTS;
  const float* zg = soa + 163840 + bb * NPTS;
  float sg0 = 0, sg1 = 0, sg2 = 0, so0 = 0, so1 = 0, so2 = 0;
  float mng0 = FLT_MAX, mng1 = FLT_MAX, mng2 = FLT_MAX;
  float mxg0 = -FLT_MAX, mxg1 = -FLT_MAX, mxg2 = -FLT_MAX;
  float mno0 = FLT_MAX, mno1 = FLT_MAX, mno2 = FLT_MAX;
  float mxo0 = -FLT_MAX, mxo1 = -FLT_MAX, mxo2 = -FLT_MAX;
  for (int j = threadIdx.x; j < NPTS; j += 256) {
    float g0 = xg[j], g1 = yg[j], g2 = zg[j];
    float o0 = xo[j], o1 = yo[j], o2 = zo[j];
    sg0 += g0; sg1 += g1; sg2 += g2; so0 += o0; so1 += o1; so2 += o2;
    mng0 = fminf(mng0, g0); mng1 = fminf(mng1, g1); mng2 = fminf(mng2, g2);
    mxg0 = fmaxf(mxg0, g0); mxg1 = fmaxf(mxg1, g1); mxg2 = fmaxf(mxg2, g2);
    mno0 = fminf(mno0, o0); mno1 = fminf(mno1, o1); mno2 = fminf(mno2, o2);
    mxo0 = fmaxf(mxo0, o0); mxo1 = fmaxf(mxo1, o1); mxo2 = fmaxf(mxo2, o2);
  }
  float mg0 = blockSum(sg0, red) * (1.0f / NPTS);
  float mg1 = blockSum(sg1, red) * (1.0f / NPTS);
  float mg2 = blockSum(sg2, red) * (1.0f / NPTS);
  float mo0 = blockSum(so0, red) * (1.0f / NPTS);
  float mo1 = blockSum(so1, red) * (1.0f / NPTS);
  float mo2 = blockSum(so2, red) * (1.0f / NPTS);
  float rg0 = blockMax(mxg0, red) - blockMin(mng0, red);
  float rg1 = blockMax(mxg1, red) - blockMin(mng1, red);
  float rg2 = blockMax(mxg2, red) - blockMin(mng2, red);
  float ro0 = blockMax(mxo0, red) - blockMin(mno0, red);
  float ro1 = blockMax(mxo1, red) - blockMin(mno1, red);
  float ro2 = blockMax(mxo2, red) - blockMin(mno2, red);
  float c00 = 0, c01 = 0, c02 = 0, c11 = 0, c12 = 0, c22 = 0;
  float q00 = 0, q01 = 0, q02 = 0, q11 = 0, q12 = 0, q22 = 0;
  float gds = 0, gd2 = 0, ods = 0, od2 = 0;
  for (int j = threadIdx.x; j < NPTS; j += 256) {
    float a0 = xg[j] - mg0, a1 = yg[j] - mg1, a2 = zg[j] - mg2;
    c00 += a0 * a0; c01 += a0 * a1; c02 += a0 * a2;
    c11 += a1 * a1; c12 += a1 * a2; c22 += a2 * a2;
    float gd = sqrtf(a0 * a0 + a1 * a1 + a2 * a2);
    gds += gd; gd2 += gd * gd;
    float b0 = xo[j] - mo0, b1 = yo[j] - mo1, b2 = zo[j] - mo2;
    q00 += b0 * b0; q01 += b0 * b1; q02 += b0 * b2;
    q11 += b1 * b1; q12 += b1 * b2; q22 += b2 * b2;
    float od = sqrtf(b0 * b0 + b1 * b1 + b2 * b2);
    ods += od; od2 += od * od;
  }
  c00 = blockSum(c00, red); c01 = blockSum(c01, red); c02 = blockSum(c02, red);
  c11 = blockSum(c11, red); c12 = blockSum(c12, red); c22 = blockSum(c22, red);
  q00 = blockSum(q00, red); q01 = blockSum(q01, red); q02 = blockSum(q02, red);
  q11 = blockSum(q11, red); q12 = blockSum(q12, red); q22 = blockSum(q22, red);
  gds = blockSum(gds, red); gd2 = blockSum(gd2, red);
  ods = blockSum(ods, red); od2 = blockSum(od2, red);
  if (threadIdx.x == 0) {
    float inv = 1.0f / (NPTS - 1);
    float d00 = (c00 - q00) * inv, d01 = (c01 - q01) * inv, d02 = (c02 - q02) * inv;
    float d11 = (c11 - q11) * inv, d12 = (c12 - q12) * inv, d22 = (c22 - q22) * inv;
    float frob = sqrtf(d00 * d00 + d11 * d11 + d22 * d22 +
                       2.0f * (d01 * d01 + d02 * d02 + d12 * d12));
    float mgd = gds * (1.0f / NPTS), mod_ = ods * (1.0f / NPTS);
    float sgd = sqrtf(fmaxf(gd2 - gds * gds * (1.0f / NPTS), 0.f) * inv);
    float sod = sqrtf(fmaxf(od2 - ods * ods * (1.0f / NPTS), 0.f) * inv);
    float centerSq = (mg0 - mo0) * (mg0 - mo0) + (mg1 - mo1) * (mg1 - mo1) +
                     (mg2 - mo2) * (mg2 - mo2);
    float r0 = rg0 - ro0, r1 = rg1 - ro1, r2 = rg2 - ro2;
    float rangeSq = r0 * r0 + r1 * r1 + r2 * r2;
    sv[bb * 7 + 0] = centerSq; sv[bb * 7 + 1] = rangeSq; sv[bb * 7 + 2] = frob;
    sv[bb * 7 + 3] = mgd; sv[bb * 7 + 4] = sgd; sv[bb * 7 + 5] = mod_; sv[bb * 7 + 6] = sod;
  }
}

// ---------- kNN: one WAVE per query, register-resident candidates, SoA loads ----
// Lane owns candidates j=(c<<6)|lane, c=0..63 (static indexing only). 8 groups
// of 8 with maintained group minima. Per pass: value-only shfl_xor min
// butterfly, ballot+ctz to find winner lane, one shfl + readfirstlane to pin
// the winner index in an SGPR (scalar-branched owner update). Self distance
// forced to -1 so pass 0 always picks self (== reference's idx[:,1:]).
template <int KSEL, bool IS_LOCAL>
__global__ __launch_bounds__(256) void knn_kernel(const float* __restrict__ soa,
                                                  int searchOfs,
                                                  float* __restrict__ outp) {
  const int lane = threadIdx.x & 63;
  const int q = (blockIdx.x << 2) + (threadIdx.x >> 6);
  const int b = q >> 12;
  const int i = q & (NPTS - 1);
  const float* xs = soa + searchOfs + b * NPTS;
  const float* ys = xs + 32768;
  const float* zs = ys + 32768;
  const float qx = xs[i], qy = ys[i], qz = zs[i];

  float cand[64];
  float gmv[8];
  int gmc[8];
  float lmv = FLT_MAX;
  int lmc = 0;
#pragma unroll
  for (int g = 0; g < 8; ++g) {
    float bv = FLT_MAX;
    int bc = 0;
#pragma unroll
    for (int u = 0; u < 8; ++u) {
      const int c = g * 8 + u;
      const int j = (c << 6) | lane;
      float dx = xs[j] - qx;
      float dy = ys[j] - qy;
      float dz = zs[j] - qz;
      float d2 = fmaf(dx, dx, fmaf(dy, dy, dz * dz));
      if (j == i) d2 = -1.0f;
      cand[c] = d2;
      if (d2 < bv) { bv = d2; bc = c; }
    }
    gmv[g] = bv; gmc[g] = bc;
    if (bv < lmv) { lmv = bv; lmc = bc; }
  }

  int mynb = 0;
  float ssum = 0.f;
  for (int k = 0; k < KSEL; ++k) {
    // value-only wave min (butterfly -> min on all lanes)
    float v = lmv;
#pragma unroll
    for (int off = 32; off; off >>= 1) v = fminf(v, __shfl_xor(v, off));
    // locate winner lane, fetch its candidate index, pin to SGPR
    unsigned long long m = __ballot(lmv == v);
    const int srclane = (int)__builtin_ctzll(m);
    int wj = __shfl((lmc << 6) | lane, srclane);
    wj = __builtin_amdgcn_readfirstlane(wj);
    if (IS_LOCAL) {
      if (lane == k - 1) mynb = wj;      // lane t records pass t+1's winner
    } else {
      if (k >= 1) ssum += sqrtf(fmaxf(v, 0.f));  // v uniform across lanes
    }
    // owner-lane incremental update (wlane/wc/wg are SGPR-uniform)
    const int wlane = wj & 63;
    const int wc = wj >> 6;
    const int wg = wc >> 3;
    if (lane == wlane) {
#pragma unroll
      for (int g = 0; g < 8; ++g) {
        if (g == wg) {
          float nv = FLT_MAX;
          int nc = 0;
#pragma unroll
          for (int u = 0; u < 8; ++u) {
            const int c = g * 8 + u;
            if (c == wc) cand[c] = FLT_MAX;
            if (cand[c] < nv) { nv = cand[c]; nc = c; }
          }
          gmv[g] = nv; gmc[g] = nc;
        }
      }
      lmv = FLT_MAX; lmc = 0;
#pragma unroll
      for (int g = 0; g < 8; ++g)
        if (gmv[g] < lmv) { lmv = gmv[g]; lmc = gmc[g]; }
    }
  }

  if (IS_LOCAL) {
    const float* gx = soa + 98304 + b * NPTS;
    const float* gy = gx + 32768;
    const float* gz = gy + 32768;
    float part = 0.f;
    if (lane < 16) {
      const int nb = mynb;
      float rx = (gx[nb] - gx[i]) - (xs[nb] - qx);
      float ry = (gy[nb] - gy[i]) - (ys[nb] - qy);
      float rz = (gz[nb] - gz[i]) - (zs[nb] - qz);
      part = fmaf(rx, rx, fmaf(ry, ry, rz * rz));
    }
#pragma unroll
    for (int off = 8; off; off >>= 1) part += __shfl_down(part, off);
    if (lane == 0) outp[q] = part;
  } else {
    if (lane == 0) outp[q] = ssum * 0.25f;
  }
}

// ---------- per-batch std1 of smooth per-row means ----------
__global__ __launch_bounds__(256) void smooth_std_kernel(const float* __restrict__ mean4,
                                                         float* __restrict__ stds) {
  __shared__ float red[4];
  int b = blockIdx.x;
  const float* p = mean4 + (size_t)b * NPTS;
  float s = 0.f;
  for (int j = threadIdx.x; j < NPTS; j += 256) s += p[j];
  s = blockSum(s, red);
  float mean = s * (1.0f / NPTS);
  float v = 0.f;
  for (int j = threadIdx.x; j < NPTS; j += 256) {
    float t = p[j] - mean;
    v += t * t;
  }
  v = blockSum(v, red);
  if (threadIdx.x == 0) stds[b] = sqrtf(v / (NPTS - 1));
}

// ---------- finalize: reduce partial arrays + combine (1 block, 256 thr) ----------
__global__ __launch_bounds__(256) void finalize_kernel(const double* __restrict__ acc,
                                                       const float* __restrict__ sv,
                                                       const float* __restrict__ stds,
                                                       const float* __restrict__ localpart,
                                                       const float* __restrict__ cpart,
                                                       float* __restrict__ out) {
  __shared__ float red[4];
  int t = threadIdx.x;
  float ls = 0.f;
  for (int j = t; j < NB * NPTS; j += 256) ls += localpart[j];
  ls = blockSum(ls, red);
  float s_sqd = 0.f, s_vo = 0.f, s_vn = 0.f, s_ab = 0.f;
  for (int j = t; j < NB * NCH; j += 256) {
    s_sqd += cpart[j];
    s_vo += cpart[2048 + j];
    s_vn += cpart[4096 + j];
    s_ab += cpart[6144 + j];
  }
  s_sqd = blockSum(s_sqd, red);
  s_vo = blockSum(s_vo, red);
  s_vn = blockSum(s_vn, red);
  s_ab = blockSum(s_ab, red);
  if (t != 0) return;

  double diff = acc[0] / (NB * (double)NPTS * 3.0);
  double cmse = (double)s_sqd / ((double)NB * NCH * NPTS);
  double ov = (double)s_vo / ((double)NB * NCH);
  double nv = (double)s_vn / ((double)NB * NCH);
  double am = (double)s_ab / ((double)NB * NCH * NPTS);
  double content = cmse + fmax(0.1 - ov, 0.0) + fmax(0.1 - nv, 0.0) +
                   fmax(1.0 - am, 0.0) * 0.1;
  double cS = 0, rS = 0, fS = 0, dmS = 0, dsS = 0;
  for (int b = 0; b < NB; b++) {
    cS += sv[b * 7 + 0]; rS += sv[b * 7 + 1]; fS += sv[b * 7 + 2];
    double dm = (double)sv[b * 7 + 3] - (double)sv[b * 7 + 5];
    dmS += dm * dm;
    double ds = (double)sv[b * 7 + 4] - (double)sv[b * 7 + 6];
    dsS += ds * ds;
  }
  double center = cS / (NB * 3.0), range = rS / (NB * 3.0), cov = fS / (double)NB;
  double dist = dmS / NB + dsS / NB;
  double shape = center + 0.5 * range + 0.1 * cov + 0.5 * dist;
  double local = (double)ls / ((double)NB * NPTS * 16.0 * 3.0);
  double smooth = 0;
  for (int b = 0; b < NB; b++) smooth += stds[b];
  smooth /= NB;
  double style = acc[5] / (double)NB;
  double total = diff + content + 2.0 * shape + local + 0.5 * smooth + 0.1 * style;
  out[0] = (float)diff;
  out[1] = (float)content;
  out[2] = (float)shape;
  out[3] = (float)local;
  out[4] = (float)smooth;
  out[5] = (float)style;
  out[6] = (float)total;
}

extern "C" void kernel_launch(void* const* d_in, const int* in_sizes, int n_in,
                              void* d_out, int out_size, void* d_ws, size_t ws_size,
                              hipStream_t stream) {
  const float* pred = (const float*)d_in[0];
  const float* targ = (const float*)d_in[1];
  const float* gen = (const float*)d_in[2];
  const float* orig = (const float*)d_in[3];
  const float* corig = (const float*)d_in[4];
  const float* cnoisy = (const float*)d_in[5];
  const float* ssrc = (const float*)d_in[6];
  const float* stgt = (const float*)d_in[7];
  float* out = (float*)d_out;

  // workspace layout (bytes)
  double* acc = (double*)d_ws;                             // [0,64)
  float* sv = (float*)((char*)d_ws + 64);                  // 56 f  [64,288)
  float* stds = (float*)((char*)d_ws + 288);               // 8 f   [288,320)
  float* mean4 = (float*)((char*)d_ws + 512);              // 32768 f [512,131584)
  float* localpart = (float*)((char*)d_ws + 131584);       // 32768 f [131584,262656)
  float* cpart = (float*)((char*)d_ws + 262656);           // 8192 f  [262656,295424)
  float* soa = (float*)((char*)d_ws + 295424);             // 196608 f [295424,1081856)

  hipMemsetAsync(d_ws, 0, 512, stream);

  prep_soa_kernel<<<256, 256, 0, stream>>>(orig, gen, soa);
  diff_kernel<<<(NB * NPTS * 3) / (4 * 256), 256, 0, stream>>>(
      (const float4*)pred, (const float4*)targ, acc);
  style_kernel<<<NB, 256, 0, stream>>>(ssrc, stgt, acc);
  content_kernel<<<NB * NCH, 256, 0, stream>>>(
      (const float4*)corig, (const float4*)cnoisy, cpart);
  shape_kernel<<<NB, 256, 0, stream>>>(soa, sv);
  knn_kernel<17, true><<<(NB * NPTS) / 4, 256, 0, stream>>>(soa, 0, localpart);
  knn_kernel<5, false><<<(NB * NPTS) / 4, 256, 0, stream>>>(soa, 98304, mean4);
  smooth_std_kernel<<<NB, 256, 0, stream>>>(mean4, stds);
  finalize_kernel<<<1, 256, 0, stream>>>(acc, sv, stds, localpart, cpart, out);
}